// Round 5
// baseline (615.875 us; speedup 1.0000x reference)
//
#include <hip/hip_runtime.h>
#include <hip/hip_bf16.h>
#include <stdint.h>

#define TSTEPS 4

typedef __bf16 bf16_t;
typedef __attribute__((ext_vector_type(8))) __bf16 bf16x8;
typedef __attribute__((ext_vector_type(4))) float f32x4;

typedef const __attribute__((address_space(1))) void* gas_ptr;
typedef __attribute__((address_space(3))) void* las_ptr;

__device__ __forceinline__ void glds16(const void* g, void* l) {
    // 16B per lane, LDS dest = wave-uniform base + lane*16
    __builtin_amdgcn_global_load_lds((gas_ptr)g, (las_ptr)l, 16, 0, 0);
}

// ---------------------------------------------------------------------------
// Stage 1: input LIF encoder (elementwise). XLA-exact rounding.
// ---------------------------------------------------------------------------
__global__ void spike_encode_kernel(const float* __restrict__ x,
                                    unsigned short* __restrict__ s1, int n)
{
    int i = blockIdx.x * blockDim.x + threadIdx.x;
    if (i >= n) return;
    float xv = x[i];
    float v = 0.0f;
#pragma unroll
    for (int t = 0; t < TSTEPS; ++t) {
        v = __fadd_rn(v, __fmul_rn(__fsub_rn(xv, v), 0.5f));
        bool sp = (v >= 1.0f);
        s1[(size_t)t * n + i] = sp ? 0x3F80 : 0;   // bf16 1.0 / 0.0
        v = sp ? 0.0f : v;
    }
}

// ---------------------------------------------------------------------------
// Weight prep: W [K][N] fp32 -> hiT, loT [N][K] bf16 (2-term split, transposed
// so B-fragments read contiguous k). Tiled transpose via LDS.
// ---------------------------------------------------------------------------
__global__ void split_transpose_kernel(const float* __restrict__ W,
                                       bf16_t* __restrict__ hiT,
                                       bf16_t* __restrict__ loT,
                                       int K, int N)
{
    __shared__ float tile[32][33];
    int k0 = blockIdx.x * 32, n0 = blockIdx.y * 32;
    int tx = threadIdx.x & 31, ty = threadIdx.x >> 5;  // 8 rows per pass
    for (int kk = ty; kk < 32; kk += 8)
        tile[kk][tx] = W[(size_t)(k0 + kk) * N + n0 + tx];
    __syncthreads();
    for (int nn = ty; nn < 32; nn += 8) {
        float w = tile[tx][nn];                 // = W[k0+tx][n0+nn]
        bf16_t h = (bf16_t)w;
        bf16_t l = (bf16_t)(w - (float)h);
        size_t o = (size_t)(n0 + nn) * K + (k0 + tx);
        hiT[o] = h;
        loT[o] = l;
    }
}

// ---------------------------------------------------------------------------
// Fused MFMA GEMM + multistep LIF.  R5: t-batched K-loop.
// A: spikes [T][M][K] bf16 (0/1 exact). WhiT/WloT: [N][K] bf16 split weights.
// Block: 128x128 tile, 4 waves of 64x64, mfma_f32_16x16x32_bf16 (R3 shape).
// K outer, all 4 timesteps accumulated simultaneously (acc[t][mt][nt], 256
// VGPRs, 1 wave/SIMD): B staged ONCE per k-chunk (was 4x), barriers /4,
// B-frag ds_reads /4. LIF t-scan runs as a register epilogue after the
// k-loop; per-t summation tree identical to R3 -> bitwise-identical spikes.
//
// LDS swizzle (R3, HW-verified): 16B chunk at slot s of row r holds global
// k-quad kq = (s - r - (r>>2)) & 3; staging dest stays lane-linear for
// global_load_lds; frag reads use p(c,r) = (c + r + (r>>2)) & 3.
// ---------------------------------------------------------------------------
template <int K, bool LAST>
__global__ __launch_bounds__(256, 1)
void gemm_lif_mfma(const unsigned short* __restrict__ A,
                   const bf16_t* __restrict__ WhiT,
                   const bf16_t* __restrict__ WloT,
                   const float* __restrict__ bias,
                   unsigned short* __restrict__ Sout,
                   float* __restrict__ Out,
                   int M, int N)
{
    constexpr int BK = 32;
    constexpr int NK = K / BK;
    __shared__ bf16_t As[TSTEPS][128 * BK];   // 4 x 8 KB
    __shared__ bf16_t Bh[128 * BK];           // 8 KB
    __shared__ bf16_t Bl[128 * BK];           // 8 KB

    const int tid = threadIdx.x;
    const int lane = tid & 63;
    const int wid = tid >> 6;
    const int il = lane & 15;
    const int q = lane >> 4;
    const int wave_m = (wid & 1) * 64;
    const int wave_n = (wid >> 1) * 64;
    const int m0 = blockIdx.x * 128;
    const int n0 = blockIdx.y * 128;

    // --- staging descriptors: 512 chunks of 16B per tile, 2 rounds/thread ---
    const int i0 = wid * 64 + lane;
    const int i1 = i0 + 256;
    const int r0 = i0 >> 2, r1 = i1 >> 2;
    const int kq0 = ((i0 & 3) - r0 - (r0 >> 2)) & 3;
    const int kq1 = ((i1 & 3) - r1 - (r1 >> 2)) & 3;

    const int ldsOff0 = (wid * 64) * 8;          // bf16 elems; +lane*16B implicit
    const int ldsOff1 = (256 + wid * 64) * 8;

    const size_t tPlane = (size_t)M * K * 2;     // bytes per timestep of A
    const size_t srcA0 = (size_t)(m0 + r0) * K * 2 + (size_t)kq0 * 16;
    const size_t srcA1 = (size_t)(m0 + r1) * K * 2 + (size_t)kq1 * 16;
    const char* pBh0 = (const char*)WhiT + (size_t)(n0 + r0) * K * 2 + kq0 * 16;
    const char* pBh1 = (const char*)WhiT + (size_t)(n0 + r1) * K * 2 + kq1 * 16;
    const char* pBl0 = (const char*)WloT + (size_t)(n0 + r0) * K * 2 + kq0 * 16;
    const char* pBl1 = (const char*)WloT + (size_t)(n0 + r1) * K * 2 + kq1 * 16;

    // --- fragment LDS byte offsets (constant) ---
    int offA[4], offB[4];
#pragma unroll
    for (int mt = 0; mt < 4; ++mt) {
        int row = wave_m + mt * 16 + il;
        int s = (q + row + (row >> 2)) & 3;
        offA[mt] = row * 64 + s * 16;
    }
#pragma unroll
    for (int nt = 0; nt < 4; ++nt) {
        int row = wave_n + nt * 16 + il;
        int s = (q + row + (row >> 2)) & 3;
        offB[nt] = row * 64 + s * 16;
    }

    float biasv[4];
#pragma unroll
    for (int nt = 0; nt < 4; ++nt)
        biasv[nt] = bias[n0 + wave_n + nt * 16 + il];

    f32x4 acc[TSTEPS][4][4];                 // 256 VGPRs: all t at once
#pragma unroll
    for (int t = 0; t < TSTEPS; ++t)
#pragma unroll
        for (int mt = 0; mt < 4; ++mt)
#pragma unroll
            for (int nt = 0; nt < 4; ++nt)
                acc[t][mt][nt] = (f32x4){0.f, 0.f, 0.f, 0.f};

    for (int kk = 0; kk < NK; ++kk) {
        const size_t kb = (size_t)kk * BK * 2;
        // stage: 4 A t-slabs + B hi/lo (B once per k-chunk -- the R5 win)
#pragma unroll
        for (int t = 0; t < TSTEPS; ++t) {
            const char* At = (const char*)A + t * tPlane;
            glds16(At + srcA0 + kb, &As[t][ldsOff0]);
            glds16(At + srcA1 + kb, &As[t][ldsOff1]);
        }
        glds16(pBh0 + kb, &Bh[ldsOff0]);
        glds16(pBh1 + kb, &Bh[ldsOff1]);
        glds16(pBl0 + kb, &Bl[ldsOff0]);
        glds16(pBl1 + kb, &Bl[ldsOff1]);
        __syncthreads();   // drains DMA -> tiles valid

        bf16x8 fh[4], fl[4];
#pragma unroll
        for (int nt = 0; nt < 4; ++nt) {
            fh[nt] = *(const bf16x8*)((const char*)Bh + offB[nt]);
            fl[nt] = *(const bf16x8*)((const char*)Bl + offB[nt]);
        }
#pragma unroll
        for (int t = 0; t < TSTEPS; ++t) {
            bf16x8 af[4];
#pragma unroll
            for (int mt = 0; mt < 4; ++mt)
                af[mt] = *(const bf16x8*)((const char*)&As[t][0] + offA[mt]);
#pragma unroll
            for (int mt = 0; mt < 4; ++mt)
#pragma unroll
                for (int nt = 0; nt < 4; ++nt) {
                    acc[t][mt][nt] = __builtin_amdgcn_mfma_f32_16x16x32_bf16(
                        af[mt], fh[nt], acc[t][mt][nt], 0, 0, 0);
                    acc[t][mt][nt] = __builtin_amdgcn_mfma_f32_16x16x32_bf16(
                        af[mt], fl[nt], acc[t][mt][nt], 0, 0, 0);
                }
        }
        __syncthreads();   // reads done before next stage overwrites
    }

    // --- LIF epilogue: t-scan in registers (XLA-exact arithmetic) ---
    f32x4 v[4][4];
    uint32_t bits[4][4];
#pragma unroll
    for (int mt = 0; mt < 4; ++mt)
#pragma unroll
        for (int nt = 0; nt < 4; ++nt) {
            v[mt][nt] = (f32x4){0.f, 0.f, 0.f, 0.f};
            bits[mt][nt] = 0u;
        }

#pragma unroll
    for (int t = 0; t < TSTEPS; ++t) {
#pragma unroll
        for (int mt = 0; mt < 4; ++mt) {
#pragma unroll
            for (int nt = 0; nt < 4; ++nt) {
#pragma unroll
                for (int r = 0; r < 4; ++r) {
                    float y = __fadd_rn(acc[t][mt][nt][r], biasv[nt]);
                    float vv = v[mt][nt][r];
                    vv = __fadd_rn(vv, __fmul_rn(__fsub_rn(y, vv), 0.5f));
                    bool sp = (vv >= 1.0f);
                    v[mt][nt][r] = sp ? 0.0f : vv;
                    if (LAST) {
                        bits[mt][nt] |= sp ? (1u << (r * 4 + t)) : 0u;
                    } else {
                        int m = m0 + wave_m + mt * 16 + q * 4 + r;
                        int n = n0 + wave_n + nt * 16 + il;
                        Sout[(size_t)t * M * N + (size_t)m * N + n] =
                            sp ? 0x3F80 : 0;
                    }
                }
            }
        }
    }

    if (LAST) {
#pragma unroll
        for (int mt = 0; mt < 4; ++mt)
#pragma unroll
            for (int nt = 0; nt < 4; ++nt)
#pragma unroll
                for (int r = 0; r < 4; ++r) {
                    int m = m0 + wave_m + mt * 16 + q * 4 + r;
                    int n = n0 + wave_n + nt * 16 + il;
                    int cnt = __popc((bits[mt][nt] >> (r * 4)) & 0xFu);
                    Out[(size_t)m * N + n] = 0.25f * (float)cnt;
                }
    }
}

// ---------------------------------------------------------------------------
// out2[b][d] = mean over L of out[b][l][d]. Exact in fp32 (quarter-integers).
// ---------------------------------------------------------------------------
__global__ void mean_over_L_kernel(const float* __restrict__ out,
                                   float* __restrict__ out2,
                                   int B, int L, int D)
{
    int id = blockIdx.x * blockDim.x + threadIdx.x;
    if (id >= B * D) return;
    int b = id / D, d = id - b * D;
    const float* p = out + (size_t)b * L * D + d;
    float s = 0.0f;
    for (int l = 0; l < L; ++l) s += p[(size_t)l * D];
    out2[id] = s * (1.0f / (float)L);
}

// ---------------------------------------------------------------------------
extern "C" void kernel_launch(void* const* d_in, const int* in_sizes, int n_in,
                              void* d_out, int out_size, void* d_ws, size_t ws_size,
                              hipStream_t stream)
{
    const float* inputs  = (const float*)d_in[0];  // [16,512,128]
    const float* enc_W   = (const float*)d_in[1];  // [128,1024]
    const float* enc_b   = (const float*)d_in[2];  // [1024]
    const float* W_cells = (const float*)d_in[3];  // [2,1024,1024]
    const float* b_cells = (const float*)d_in[4];  // [2,1024]

    const int B = 16, L = 512, C = 128, D = 1024;
    const int M = B * L;  // 8192

    // ws layout: s1 8MB | W1h/l 0.5MB | W2h/l 4MB | W3h/l 4MB | h0 64MB | h1 64MB
    char* ws = (char*)d_ws;
    size_t off = 0;
    unsigned short* s1 = (unsigned short*)(ws + off); off += (size_t)TSTEPS * M * C * 2;
    bf16_t* W1h = (bf16_t*)(ws + off); off += (size_t)C * D * 2;
    bf16_t* W1l = (bf16_t*)(ws + off); off += (size_t)C * D * 2;
    bf16_t* W2h = (bf16_t*)(ws + off); off += (size_t)D * D * 2;
    bf16_t* W2l = (bf16_t*)(ws + off); off += (size_t)D * D * 2;
    bf16_t* W3h = (bf16_t*)(ws + off); off += (size_t)D * D * 2;
    bf16_t* W3l = (bf16_t*)(ws + off); off += (size_t)D * D * 2;
    unsigned short* h0 = (unsigned short*)(ws + off); off += (size_t)TSTEPS * M * D * 2;
    unsigned short* h1 = (unsigned short*)(ws + off);

    float* out  = (float*)d_out;          // [M, D]
    float* out2 = out + (size_t)M * D;    // [B, D]

    split_transpose_kernel<<<dim3(C / 32, D / 32), 256, 0, stream>>>(
        enc_W, W1h, W1l, C, D);
    split_transpose_kernel<<<dim3(D / 32, D / 32), 256, 0, stream>>>(
        W_cells, W2h, W2l, D, D);
    split_transpose_kernel<<<dim3(D / 32, D / 32), 256, 0, stream>>>(
        W_cells + (size_t)D * D, W3h, W3l, D, D);

    const int n1 = M * C;
    spike_encode_kernel<<<(n1 + 255) / 256, 256, 0, stream>>>(inputs, s1, n1);

    dim3 grid(M / 128, D / 128);
    gemm_lif_mfma<128, false><<<grid, 256, 0, stream>>>(
        s1, W1h, W1l, enc_b, h0, nullptr, M, D);
    gemm_lif_mfma<1024, false><<<grid, 256, 0, stream>>>(
        h0, W2h, W2l, b_cells, h1, nullptr, M, D);
    gemm_lif_mfma<1024, true><<<grid, 256, 0, stream>>>(
        h1, W3h, W3l, b_cells + D, nullptr, out, M, D);

    mean_over_L_kernel<<<(B * D + 255) / 256, 256, 0, stream>>>(
        out, out2, B, L, D);
}

// Round 6
// 580.464 us; speedup vs baseline: 1.0610x; 1.0610x over previous
//
#include <hip/hip_runtime.h>
#include <hip/hip_bf16.h>
#include <stdint.h>

#define TSTEPS 4

typedef __bf16 bf16_t;
typedef __attribute__((ext_vector_type(8))) __bf16 bf16x8;
typedef __attribute__((ext_vector_type(4))) float f32x4;

typedef const __attribute__((address_space(1))) void* gas_ptr;
typedef __attribute__((address_space(3))) void* las_ptr;

__device__ __forceinline__ void glds16(const void* g, void* l) {
    // 16B per lane, LDS dest = wave-uniform base + lane*16
    __builtin_amdgcn_global_load_lds((gas_ptr)g, (las_ptr)l, 16, 0, 0);
}

// ---------------------------------------------------------------------------
// Stage 1: input LIF encoder (elementwise). XLA-exact rounding.
// ---------------------------------------------------------------------------
__global__ void spike_encode_kernel(const float* __restrict__ x,
                                    unsigned short* __restrict__ s1, int n)
{
    int i = blockIdx.x * blockDim.x + threadIdx.x;
    if (i >= n) return;
    float xv = x[i];
    float v = 0.0f;
#pragma unroll
    for (int t = 0; t < TSTEPS; ++t) {
        v = __fadd_rn(v, __fmul_rn(__fsub_rn(xv, v), 0.5f));
        bool sp = (v >= 1.0f);
        s1[(size_t)t * n + i] = sp ? 0x3F80 : 0;   // bf16 1.0 / 0.0
        v = sp ? 0.0f : v;
    }
}

// ---------------------------------------------------------------------------
// Weight prep, all 3 matrices in one launch (fewer graph nodes).
// W [K][N] fp32 -> hiT, loT [N][K] bf16 (2-term split, transposed).
// grid = (32, 32, 3); z=0 handles enc_W (K=128, only x<4 active).
// ---------------------------------------------------------------------------
__global__ void split_transpose_all(const float* __restrict__ enc_W,
                                    const float* __restrict__ W_cells,
                                    bf16_t* __restrict__ W1h, bf16_t* __restrict__ W1l,
                                    bf16_t* __restrict__ W2h, bf16_t* __restrict__ W2l,
                                    bf16_t* __restrict__ W3h, bf16_t* __restrict__ W3l)
{
    const int N = 1024;
    const float* W;
    bf16_t *hi, *lo;
    int K;
    if (blockIdx.z == 0) {
        if (blockIdx.x >= 4) return;
        W = enc_W; hi = W1h; lo = W1l; K = 128;
    } else if (blockIdx.z == 1) {
        W = W_cells; hi = W2h; lo = W2l; K = 1024;
    } else {
        W = W_cells + (size_t)1024 * 1024; hi = W3h; lo = W3l; K = 1024;
    }
    __shared__ float tile[32][33];
    int k0 = blockIdx.x * 32, n0 = blockIdx.y * 32;
    int tx = threadIdx.x & 31, ty = threadIdx.x >> 5;  // 8 rows per pass
    for (int kk = ty; kk < 32; kk += 8)
        tile[kk][tx] = W[(size_t)(k0 + kk) * N + n0 + tx];
    __syncthreads();
    for (int nn = ty; nn < 32; nn += 8) {
        float w = tile[tx][nn];                 // = W[k0+tx][n0+nn]
        bf16_t h = (bf16_t)w;
        bf16_t l = (bf16_t)(w - (float)h);
        size_t o = (size_t)(n0 + nn) * K + (k0 + tx);
        hi[o] = h;
        lo[o] = l;
    }
}

// ---------------------------------------------------------------------------
// Fused MFMA GEMM + multistep LIF.  R6: tau=2 t-batch + prefetch distance.
// A: spikes [T][M][K] bf16 (0/1 exact). WhiT/WloT: [N][K] bf16 split weights.
// Block: 512 threads, 128x128 tile, 8 waves of 64x32 (wave grid 2m x 4n),
// mfma_f32_16x16x32_bf16. Two passes (t={0,1}, t={2,3}); each pass's K-loop
// accumulates acc[2][4][2] (64 VGPR) for both timesteps, staging B once per
// k-chunk for 2 t's. LIF membrane v[4][2] carried across passes in registers.
//
// K-loop iteration (the drain fix):
//   read B frags -> barrier -> stage chunk k+1 (A into OTHER buffer, B into
//   same) -> 32 MFMAs reading A lazily from current buffer -> barrier(drain)
// The vmcnt(0) drain at the 2nd barrier waits on DMA issued a full MFMA
// phase earlier, instead of just-issued (R3's exposed ~875 cyc/iter).
//
// LDS swizzle (R3, HW-verified): 16B chunk i -> row r=i>>2 holds k-quad
// kq = ((i&3) - r - (r>>2)) & 3; frag read slot s = (q + row + (row>>2)) & 3.
// ---------------------------------------------------------------------------
template <int K, bool LAST>
__global__ __launch_bounds__(512, 2)
void gemm_lif_mfma(const unsigned short* __restrict__ A,
                   const bf16_t* __restrict__ WhiT,
                   const bf16_t* __restrict__ WloT,
                   const float* __restrict__ bias,
                   unsigned short* __restrict__ Sout,
                   float* __restrict__ Out,
                   int M, int N)
{
    constexpr int BK = 32;
    constexpr int NK = K / BK;
    __shared__ bf16_t As[2][2][128 * BK];  // [buf][tt] : 32 KB
    __shared__ bf16_t Bh[128 * BK];        // 8 KB
    __shared__ bf16_t Bl[128 * BK];        // 8 KB

    const int tid = threadIdx.x;
    const int lane = tid & 63;
    const int wid = tid >> 6;            // 0..7
    const int il = lane & 15;
    const int q = lane >> 4;
    const int wave_m = (wid >> 2) * 64;  // 0 / 64
    const int wave_n = (wid & 3) * 32;   // 0,32,64,96
    const int m0 = blockIdx.x * 128;
    const int n0 = blockIdx.y * 128;

    // --- staging: chunk i = tid (512 x 16B chunks per 8KB tile) ---
    const int r = tid >> 2;                        // 0..127
    const int kq = ((tid & 3) - r - (r >> 2)) & 3;
    const int ldsBase = wid * 512;                 // bf16 elems; wave-uniform

    const size_t tPlane = (size_t)M * K * 2;
    const size_t srcA = (size_t)(m0 + r) * K * 2 + (size_t)kq * 16;
    const char* pBh = (const char*)WhiT + (size_t)(n0 + r) * K * 2 + kq * 16;
    const char* pBl = (const char*)WloT + (size_t)(n0 + r) * K * 2 + kq * 16;

    // --- fragment LDS byte offsets ---
    int offA[4], offB[2];
#pragma unroll
    for (int mt = 0; mt < 4; ++mt) {
        int row = wave_m + mt * 16 + il;
        int s = (q + row + (row >> 2)) & 3;
        offA[mt] = row * 64 + s * 16;
    }
#pragma unroll
    for (int nt = 0; nt < 2; ++nt) {
        int row = wave_n + nt * 16 + il;
        int s = (q + row + (row >> 2)) & 3;
        offB[nt] = row * 64 + s * 16;
    }

    float biasv[2];
#pragma unroll
    for (int nt = 0; nt < 2; ++nt)
        biasv[nt] = bias[n0 + wave_n + nt * 16 + il];

    f32x4 v[4][2];
    uint32_t bits[4][2];
#pragma unroll
    for (int mt = 0; mt < 4; ++mt)
#pragma unroll
        for (int nt = 0; nt < 2; ++nt) {
            v[mt][nt] = (f32x4){0.f, 0.f, 0.f, 0.f};
            bits[mt][nt] = 0u;
        }

    for (int pass = 0; pass < 2; ++pass) {
        const char* At0 = (const char*)A + (size_t)(2 * pass + 0) * tPlane;
        const char* At1 = (const char*)A + (size_t)(2 * pass + 1) * tPlane;

        f32x4 acc[2][4][2];
#pragma unroll
        for (int tt = 0; tt < 2; ++tt)
#pragma unroll
            for (int mt = 0; mt < 4; ++mt)
#pragma unroll
                for (int nt = 0; nt < 2; ++nt)
                    acc[tt][mt][nt] = (f32x4){0.f, 0.f, 0.f, 0.f};

        // prologue: chunk 0 -> A buf 0, B
        glds16(At0 + srcA, &As[0][0][ldsBase]);
        glds16(At1 + srcA, &As[0][1][ldsBase]);
        glds16(pBh, &Bh[ldsBase]);
        glds16(pBl, &Bl[ldsBase]);
        __syncthreads();

        for (int kk = 0; kk < NK; ++kk) {
            const int cur = kk & 1, nxt = cur ^ 1;

            // B fragments must be in regs before barrier (B single-buffered)
            bf16x8 fh[2], fl[2];
#pragma unroll
            for (int nt = 0; nt < 2; ++nt) {
                fh[nt] = *(const bf16x8*)((const char*)Bh + offB[nt]);
                fl[nt] = *(const bf16x8*)((const char*)Bl + offB[nt]);
            }
            __syncthreads();   // all B reads done; A cur-buf reads still ahead

            if (kk + 1 < NK) {
                const size_t kb = (size_t)(kk + 1) * BK * 2;
                glds16(At0 + srcA + kb, &As[nxt][0][ldsBase]);
                glds16(At1 + srcA + kb, &As[nxt][1][ldsBase]);
                glds16(pBh + kb, &Bh[ldsBase]);
                glds16(pBl + kb, &Bl[ldsBase]);
            }

            // MFMA phase: A read lazily from current buffer (disjoint from DMA)
#pragma unroll
            for (int mt = 0; mt < 4; ++mt) {
                bf16x8 a0 = *(const bf16x8*)((const char*)&As[cur][0][0] + offA[mt]);
                bf16x8 a1 = *(const bf16x8*)((const char*)&As[cur][1][0] + offA[mt]);
#pragma unroll
                for (int nt = 0; nt < 2; ++nt) {
                    acc[0][mt][nt] = __builtin_amdgcn_mfma_f32_16x16x32_bf16(
                        a0, fh[nt], acc[0][mt][nt], 0, 0, 0);
                    acc[0][mt][nt] = __builtin_amdgcn_mfma_f32_16x16x32_bf16(
                        a0, fl[nt], acc[0][mt][nt], 0, 0, 0);
                    acc[1][mt][nt] = __builtin_amdgcn_mfma_f32_16x16x32_bf16(
                        a1, fh[nt], acc[1][mt][nt], 0, 0, 0);
                    acc[1][mt][nt] = __builtin_amdgcn_mfma_f32_16x16x32_bf16(
                        a1, fl[nt], acc[1][mt][nt], 0, 0, 0);
                }
            }
            __syncthreads();   // drains DMA (issued one MFMA phase ago)
        }

        // --- LIF epilogue for t = 2*pass, 2*pass+1 (XLA-exact arithmetic) ---
#pragma unroll
        for (int tt = 0; tt < 2; ++tt) {
            const int t = 2 * pass + tt;
#pragma unroll
            for (int mt = 0; mt < 4; ++mt)
#pragma unroll
                for (int nt = 0; nt < 2; ++nt)
#pragma unroll
                    for (int rr = 0; rr < 4; ++rr) {
                        float y = __fadd_rn(acc[tt][mt][nt][rr], biasv[nt]);
                        float vv = v[mt][nt][rr];
                        vv = __fadd_rn(vv, __fmul_rn(__fsub_rn(y, vv), 0.5f));
                        bool sp = (vv >= 1.0f);
                        v[mt][nt][rr] = sp ? 0.0f : vv;
                        if (LAST) {
                            bits[mt][nt] |= sp ? (1u << (rr * 4 + t)) : 0u;
                        } else {
                            int m = m0 + wave_m + mt * 16 + q * 4 + rr;
                            int n = n0 + wave_n + nt * 16 + il;
                            Sout[(size_t)t * M * N + (size_t)m * N + n] =
                                sp ? 0x3F80 : 0;
                        }
                    }
        }
    }

    if (LAST) {
#pragma unroll
        for (int mt = 0; mt < 4; ++mt)
#pragma unroll
            for (int nt = 0; nt < 2; ++nt)
#pragma unroll
                for (int rr = 0; rr < 4; ++rr) {
                    int m = m0 + wave_m + mt * 16 + q * 4 + rr;
                    int n = n0 + wave_n + nt * 16 + il;
                    int cnt = __popc((bits[mt][nt] >> (rr * 4)) & 0xFu);
                    Out[(size_t)m * N + n] = 0.25f * (float)cnt;
                }
    }
}

// ---------------------------------------------------------------------------
// out2[b][d] = mean over L of out[b][l][d]. Exact in fp32 (quarter-integers).
// ---------------------------------------------------------------------------
__global__ void mean_over_L_kernel(const float* __restrict__ out,
                                   float* __restrict__ out2,
                                   int B, int L, int D)
{
    int id = blockIdx.x * blockDim.x + threadIdx.x;
    if (id >= B * D) return;
    int b = id / D, d = id - b * D;
    const float* p = out + (size_t)b * L * D + d;
    float s = 0.0f;
    for (int l = 0; l < L; ++l) s += p[(size_t)l * D];
    out2[id] = s * (1.0f / (float)L);
}

// ---------------------------------------------------------------------------
extern "C" void kernel_launch(void* const* d_in, const int* in_sizes, int n_in,
                              void* d_out, int out_size, void* d_ws, size_t ws_size,
                              hipStream_t stream)
{
    const float* inputs  = (const float*)d_in[0];  // [16,512,128]
    const float* enc_W   = (const float*)d_in[1];  // [128,1024]
    const float* enc_b   = (const float*)d_in[2];  // [1024]
    const float* W_cells = (const float*)d_in[3];  // [2,1024,1024]
    const float* b_cells = (const float*)d_in[4];  // [2,1024]

    const int B = 16, L = 512, C = 128, D = 1024;
    const int M = B * L;  // 8192

    // ws layout: s1 8MB | W1h/l 0.5MB | W2h/l 4MB | W3h/l 4MB | h0 64MB | h1 64MB
    char* ws = (char*)d_ws;
    size_t off = 0;
    unsigned short* s1 = (unsigned short*)(ws + off); off += (size_t)TSTEPS * M * C * 2;
    bf16_t* W1h = (bf16_t*)(ws + off); off += (size_t)C * D * 2;
    bf16_t* W1l = (bf16_t*)(ws + off); off += (size_t)C * D * 2;
    bf16_t* W2h = (bf16_t*)(ws + off); off += (size_t)D * D * 2;
    bf16_t* W2l = (bf16_t*)(ws + off); off += (size_t)D * D * 2;
    bf16_t* W3h = (bf16_t*)(ws + off); off += (size_t)D * D * 2;
    bf16_t* W3l = (bf16_t*)(ws + off); off += (size_t)D * D * 2;
    unsigned short* h0 = (unsigned short*)(ws + off); off += (size_t)TSTEPS * M * D * 2;
    unsigned short* h1 = (unsigned short*)(ws + off);

    float* out  = (float*)d_out;          // [M, D]
    float* out2 = out + (size_t)M * D;    // [B, D]

    split_transpose_all<<<dim3(32, 32, 3), 256, 0, stream>>>(
        enc_W, W_cells, W1h, W1l, W2h, W2l, W3h, W3l);

    const int n1 = M * C;
    spike_encode_kernel<<<(n1 + 255) / 256, 256, 0, stream>>>(inputs, s1, n1);

    dim3 grid(M / 128, D / 128);
    gemm_lif_mfma<128, false><<<grid, 512, 0, stream>>>(
        s1, W1h, W1l, enc_b, h0, nullptr, M, D);
    gemm_lif_mfma<1024, false><<<grid, 512, 0, stream>>>(
        h0, W2h, W2l, b_cells, h1, nullptr, M, D);
    gemm_lif_mfma<1024, true><<<grid, 512, 0, stream>>>(
        h1, W3h, W3l, b_cells + D, nullptr, out, M, D);

    mean_over_L_kernel<<<(B * D + 255) / 256, 256, 0, stream>>>(
        out, out2, B, L, D);
}

// Round 7
// 492.948 us; speedup vs baseline: 1.2494x; 1.1775x over previous
//
#include <hip/hip_runtime.h>
#include <hip/hip_bf16.h>
#include <stdint.h>

#define TSTEPS 4

typedef __bf16 bf16_t;
typedef __attribute__((ext_vector_type(8))) __bf16 bf16x8;
typedef __attribute__((ext_vector_type(4))) float f32x4;

typedef const __attribute__((address_space(1))) void* gas_ptr;
typedef __attribute__((address_space(3))) void* las_ptr;

__device__ __forceinline__ void glds16(const void* g, void* l) {
    // 16B per lane, LDS dest = wave-uniform base + lane*16
    __builtin_amdgcn_global_load_lds((gas_ptr)g, (las_ptr)l, 16, 0, 0);
}

// gfx9 s_waitcnt immediates: vmcnt[3:0]|[15:14], expcnt[6:4], lgkmcnt[11:8]
// (expcnt=7, lgkmcnt=15 = don't wait)
#define WAITCNT_VM6 0xF76   // vmcnt(6)
#define WAITCNT_VM0 0xF70   // vmcnt(0)

// ---------------------------------------------------------------------------
// Stage 1: input LIF encoder (elementwise). XLA-exact rounding.
// ---------------------------------------------------------------------------
__global__ void spike_encode_kernel(const float* __restrict__ x,
                                    unsigned short* __restrict__ s1, int n)
{
    int i = blockIdx.x * blockDim.x + threadIdx.x;
    if (i >= n) return;
    float xv = x[i];
    float v = 0.0f;
#pragma unroll
    for (int t = 0; t < TSTEPS; ++t) {
        v = __fadd_rn(v, __fmul_rn(__fsub_rn(xv, v), 0.5f));
        bool sp = (v >= 1.0f);
        s1[(size_t)t * n + i] = sp ? 0x3F80 : 0;   // bf16 1.0 / 0.0
        v = sp ? 0.0f : v;
    }
}

// ---------------------------------------------------------------------------
// Weight prep, all 3 matrices in one launch.
// W [K][N] fp32 -> hiT, loT [N][K] bf16 (2-term split, transposed).
// ---------------------------------------------------------------------------
__global__ void split_transpose_all(const float* __restrict__ enc_W,
                                    const float* __restrict__ W_cells,
                                    bf16_t* __restrict__ W1h, bf16_t* __restrict__ W1l,
                                    bf16_t* __restrict__ W2h, bf16_t* __restrict__ W2l,
                                    bf16_t* __restrict__ W3h, bf16_t* __restrict__ W3l)
{
    const int N = 1024;
    const float* W;
    bf16_t *hi, *lo;
    int K;
    if (blockIdx.z == 0) {
        if (blockIdx.x >= 4) return;
        W = enc_W; hi = W1h; lo = W1l; K = 128;
    } else if (blockIdx.z == 1) {
        W = W_cells; hi = W2h; lo = W2l; K = 1024;
    } else {
        W = W_cells + (size_t)1024 * 1024; hi = W3h; lo = W3l; K = 1024;
    }
    __shared__ float tile[32][33];
    int k0 = blockIdx.x * 32, n0 = blockIdx.y * 32;
    int tx = threadIdx.x & 31, ty = threadIdx.x >> 5;
    for (int kk = ty; kk < 32; kk += 8)
        tile[kk][tx] = W[(size_t)(k0 + kk) * N + n0 + tx];
    __syncthreads();
    for (int nn = ty; nn < 32; nn += 8) {
        float w = tile[tx][nn];
        bf16_t h = (bf16_t)w;
        bf16_t l = (bf16_t)(w - (float)h);
        size_t o = (size_t)(n0 + nn) * K + (k0 + tx);
        hi[o] = h;
        lo[o] = l;
    }
}

// ---------------------------------------------------------------------------
// Fused MFMA GEMM + multistep LIF.  R7 = R3 structure + fine-grained vmcnt.
// A: spikes [T][M][K] bf16 (0/1 exact). WhiT/WloT: [N][K] bf16 split weights.
// Block: 128x128 tile, 4 waves of 64x64, mfma_f32_16x16x32_bf16, t-outer.
//
// K-loop (the R7 change): ring-2 LDS buffers; per iter
//   issue 6 DMA for k+1 -> other buf
//   s_waitcnt vmcnt(6)      <- waits only k's loads, issued a FULL ITER ago
//   s_barrier (raw)         <- no vmcnt(0) drain, unlike __syncthreads
//   ds_read + 32 MFMA from current buf
//   s_barrier (raw)         <- WAR: next iter's DMA may overwrite other buf
// Hazards: stage(k+1) targets buf[(k+1)&1], last read in iter k-1, protected
// by the trailing barrier of k-1; in-flight DMA is disjoint from read buf.
//
// LDS swizzle (R3, HW-verified): 16B chunk i -> row r=i>>2 holds k-quad
// kq = ((i&3) - r - (r>>2)) & 3; frag read slot s = (q + row + (row>>2)) & 3.
// ---------------------------------------------------------------------------
template <int K, bool LAST>
__global__ __launch_bounds__(256, 2)
void gemm_lif_mfma(const unsigned short* __restrict__ A,
                   const bf16_t* __restrict__ WhiT,
                   const bf16_t* __restrict__ WloT,
                   const float* __restrict__ bias,
                   unsigned short* __restrict__ Sout,
                   float* __restrict__ Out,
                   int M, int N)
{
    constexpr int BK = 32;
    constexpr int NK = K / BK;
    __shared__ bf16_t As[2][128 * BK];   // ring-2: 2 x 8 KB each
    __shared__ bf16_t Bh[2][128 * BK];
    __shared__ bf16_t Bl[2][128 * BK];

    const int tid = threadIdx.x;
    const int lane = tid & 63;
    const int wid = tid >> 6;
    const int il = lane & 15;
    const int q = lane >> 4;
    const int wave_m = (wid & 1) * 64;
    const int wave_n = (wid >> 1) * 64;
    const int m0 = blockIdx.x * 128;
    const int n0 = blockIdx.y * 128;

    // --- staging: 512 chunks of 16B per tile, 2 rounds/thread ---
    const int i0 = wid * 64 + lane;
    const int i1 = i0 + 256;
    const int r0 = i0 >> 2, r1 = i1 >> 2;
    const int kq0 = ((i0 & 3) - r0 - (r0 >> 2)) & 3;
    const int kq1 = ((i1 & 3) - r1 - (r1 >> 2)) & 3;

    const int ldsOff0 = (wid * 64) * 8;          // bf16 elems; +lane*16B implicit
    const int ldsOff1 = (256 + wid * 64) * 8;

    const size_t srcA0 = (size_t)(m0 + r0) * K * 2 + (size_t)kq0 * 16;
    const size_t srcA1 = (size_t)(m0 + r1) * K * 2 + (size_t)kq1 * 16;
    const char* pBh0 = (const char*)WhiT + (size_t)(n0 + r0) * K * 2 + kq0 * 16;
    const char* pBh1 = (const char*)WhiT + (size_t)(n0 + r1) * K * 2 + kq1 * 16;
    const char* pBl0 = (const char*)WloT + (size_t)(n0 + r0) * K * 2 + kq0 * 16;
    const char* pBl1 = (const char*)WloT + (size_t)(n0 + r1) * K * 2 + kq1 * 16;

    // --- fragment LDS byte offsets (within one buffer) ---
    int offA[4], offB[4];
#pragma unroll
    for (int mt = 0; mt < 4; ++mt) {
        int row = wave_m + mt * 16 + il;
        int s = (q + row + (row >> 2)) & 3;
        offA[mt] = row * 64 + s * 16;
    }
#pragma unroll
    for (int nt = 0; nt < 4; ++nt) {
        int row = wave_n + nt * 16 + il;
        int s = (q + row + (row >> 2)) & 3;
        offB[nt] = row * 64 + s * 16;
    }

    float biasv[4];
#pragma unroll
    for (int nt = 0; nt < 4; ++nt)
        biasv[nt] = bias[n0 + wave_n + nt * 16 + il];

    f32x4 v[4][4];
    uint32_t bits[4][4];
#pragma unroll
    for (int mt = 0; mt < 4; ++mt)
#pragma unroll
        for (int nt = 0; nt < 4; ++nt) {
            v[mt][nt] = (f32x4){0.f, 0.f, 0.f, 0.f};
            bits[mt][nt] = 0u;
        }

    for (int t = 0; t < TSTEPS; ++t) {
        const char* At = (const char*)A + (size_t)t * M * K * 2;
        f32x4 acc[4][4];
#pragma unroll
        for (int mt = 0; mt < 4; ++mt)
#pragma unroll
            for (int nt = 0; nt < 4; ++nt)
                acc[mt][nt] = (f32x4){0.f, 0.f, 0.f, 0.f};

        // prologue: chunk 0 -> buf 0
        glds16(At + srcA0, &As[0][ldsOff0]);
        glds16(At + srcA1, &As[0][ldsOff1]);
        glds16(pBh0, &Bh[0][ldsOff0]);
        glds16(pBh1, &Bh[0][ldsOff1]);
        glds16(pBl0, &Bl[0][ldsOff0]);
        glds16(pBl1, &Bl[0][ldsOff1]);

        for (int kk = 0; kk < NK; ++kk) {
            const int cur = kk & 1, nxt = cur ^ 1;

            if (kk + 1 < NK) {
                const size_t kb = (size_t)(kk + 1) * BK * 2;
                glds16(At + srcA0 + kb, &As[nxt][ldsOff0]);
                glds16(At + srcA1 + kb, &As[nxt][ldsOff1]);
                glds16(pBh0 + kb, &Bh[nxt][ldsOff0]);
                glds16(pBh1 + kb, &Bh[nxt][ldsOff1]);
                glds16(pBl0 + kb, &Bl[nxt][ldsOff0]);
                glds16(pBl1 + kb, &Bl[nxt][ldsOff1]);
                __builtin_amdgcn_s_waitcnt(WAITCNT_VM6);  // k's loads landed
            } else {
                __builtin_amdgcn_s_waitcnt(WAITCNT_VM0);
            }
            asm volatile("" ::: "memory");
            __builtin_amdgcn_s_barrier();   // raw: no vmcnt(0) drain
            asm volatile("" ::: "memory");

            bf16x8 af[4], fh[4], fl[4];
#pragma unroll
            for (int mt = 0; mt < 4; ++mt)
                af[mt] = *(const bf16x8*)((const char*)&As[cur][0] + offA[mt]);
#pragma unroll
            for (int nt = 0; nt < 4; ++nt) {
                fh[nt] = *(const bf16x8*)((const char*)&Bh[cur][0] + offB[nt]);
                fl[nt] = *(const bf16x8*)((const char*)&Bl[cur][0] + offB[nt]);
            }
#pragma unroll
            for (int mt = 0; mt < 4; ++mt)
#pragma unroll
                for (int nt = 0; nt < 4; ++nt) {
                    acc[mt][nt] = __builtin_amdgcn_mfma_f32_16x16x32_bf16(
                        af[mt], fh[nt], acc[mt][nt], 0, 0, 0);
                    acc[mt][nt] = __builtin_amdgcn_mfma_f32_16x16x32_bf16(
                        af[mt], fl[nt], acc[mt][nt], 0, 0, 0);
                }
            asm volatile("" ::: "memory");
            __builtin_amdgcn_s_barrier();   // WAR sync before buf reuse
            asm volatile("" ::: "memory");
        }

        // --- LIF epilogue for timestep t (XLA-exact scan arithmetic) ---
#pragma unroll
        for (int mt = 0; mt < 4; ++mt)
#pragma unroll
            for (int nt = 0; nt < 4; ++nt)
#pragma unroll
                for (int r = 0; r < 4; ++r) {
                    float y = __fadd_rn(acc[mt][nt][r], biasv[nt]);
                    float vv = v[mt][nt][r];
                    vv = __fadd_rn(vv, __fmul_rn(__fsub_rn(y, vv), 0.5f));
                    bool sp = (vv >= 1.0f);
                    v[mt][nt][r] = sp ? 0.0f : vv;
                    if (LAST) {
                        bits[mt][nt] |= sp ? (1u << (r * 4 + t)) : 0u;
                    } else {
                        int m = m0 + wave_m + mt * 16 + q * 4 + r;
                        int n = n0 + wave_n + nt * 16 + il;
                        Sout[(size_t)t * M * N + (size_t)m * N + n] =
                            sp ? 0x3F80 : 0;
                    }
                }
    }

    if (LAST) {
#pragma unroll
        for (int mt = 0; mt < 4; ++mt)
#pragma unroll
            for (int nt = 0; nt < 4; ++nt)
#pragma unroll
                for (int r = 0; r < 4; ++r) {
                    int m = m0 + wave_m + mt * 16 + q * 4 + r;
                    int n = n0 + wave_n + nt * 16 + il;
                    int cnt = __popc((bits[mt][nt] >> (r * 4)) & 0xFu);
                    Out[(size_t)m * N + n] = 0.25f * (float)cnt;
                }
    }
}

// ---------------------------------------------------------------------------
// out2[b][d] = mean over L of out[b][l][d]. Exact in fp32 (quarter-integers).
// ---------------------------------------------------------------------------
__global__ void mean_over_L_kernel(const float* __restrict__ out,
                                   float* __restrict__ out2,
                                   int B, int L, int D)
{
    int id = blockIdx.x * blockDim.x + threadIdx.x;
    if (id >= B * D) return;
    int b = id / D, d = id - b * D;
    const float* p = out + (size_t)b * L * D + d;
    float s = 0.0f;
    for (int l = 0; l < L; ++l) s += p[(size_t)l * D];
    out2[id] = s * (1.0f / (float)L);
}

// ---------------------------------------------------------------------------
extern "C" void kernel_launch(void* const* d_in, const int* in_sizes, int n_in,
                              void* d_out, int out_size, void* d_ws, size_t ws_size,
                              hipStream_t stream)
{
    const float* inputs  = (const float*)d_in[0];  // [16,512,128]
    const float* enc_W   = (const float*)d_in[1];  // [128,1024]
    const float* enc_b   = (const float*)d_in[2];  // [1024]
    const float* W_cells = (const float*)d_in[3];  // [2,1024,1024]
    const float* b_cells = (const float*)d_in[4];  // [2,1024]

    const int B = 16, L = 512, C = 128, D = 1024;
    const int M = B * L;  // 8192

    // ws layout: s1 8MB | W1h/l 0.5MB | W2h/l 4MB | W3h/l 4MB | h0 64MB | h1 64MB
    char* ws = (char*)d_ws;
    size_t off = 0;
    unsigned short* s1 = (unsigned short*)(ws + off); off += (size_t)TSTEPS * M * C * 2;
    bf16_t* W1h = (bf16_t*)(ws + off); off += (size_t)C * D * 2;
    bf16_t* W1l = (bf16_t*)(ws + off); off += (size_t)C * D * 2;
    bf16_t* W2h = (bf16_t*)(ws + off); off += (size_t)D * D * 2;
    bf16_t* W2l = (bf16_t*)(ws + off); off += (size_t)D * D * 2;
    bf16_t* W3h = (bf16_t*)(ws + off); off += (size_t)D * D * 2;
    bf16_t* W3l = (bf16_t*)(ws + off); off += (size_t)D * D * 2;
    unsigned short* h0 = (unsigned short*)(ws + off); off += (size_t)TSTEPS * M * D * 2;
    unsigned short* h1 = (unsigned short*)(ws + off);

    float* out  = (float*)d_out;          // [M, D]
    float* out2 = out + (size_t)M * D;    // [B, D]

    split_transpose_all<<<dim3(32, 32, 3), 256, 0, stream>>>(
        enc_W, W_cells, W1h, W1l, W2h, W2l, W3h, W3l);

    const int n1 = M * C;
    spike_encode_kernel<<<(n1 + 255) / 256, 256, 0, stream>>>(inputs, s1, n1);

    dim3 grid(M / 128, D / 128);
    gemm_lif_mfma<128, false><<<grid, 256, 0, stream>>>(
        s1, W1h, W1l, enc_b, h0, nullptr, M, D);
    gemm_lif_mfma<1024, false><<<grid, 256, 0, stream>>>(
        h0, W2h, W2l, b_cells, h1, nullptr, M, D);
    gemm_lif_mfma<1024, true><<<grid, 256, 0, stream>>>(
        h1, W3h, W3l, b_cells + D, nullptr, out, M, D);

    mean_over_L_kernel<<<(B * D + 255) / 256, 256, 0, stream>>>(
        out, out2, B, L, D);
}

// Round 8
// 488.891 us; speedup vs baseline: 1.2597x; 1.0083x over previous
//
#include <hip/hip_runtime.h>
#include <hip/hip_bf16.h>
#include <stdint.h>

#define TSTEPS 4

typedef __bf16 bf16_t;
typedef __attribute__((ext_vector_type(8))) __bf16 bf16x8;
typedef __attribute__((ext_vector_type(16))) float f32x16;

typedef const __attribute__((address_space(1))) void* gas_ptr;
typedef __attribute__((address_space(3))) void* las_ptr;

__device__ __forceinline__ void glds16(const void* g, void* l) {
    // 16B per lane, LDS dest = wave-uniform base + lane*16
    __builtin_amdgcn_global_load_lds((gas_ptr)g, (las_ptr)l, 16, 0, 0);
}

// gfx9 s_waitcnt immediates: vmcnt[3:0]|[15:14], expcnt[6:4], lgkmcnt[11:8]
#define WAITCNT_VM6 0xF76   // vmcnt(6)
#define WAITCNT_VM0 0xF70   // vmcnt(0)

// ---------------------------------------------------------------------------
// Stage 1: input LIF encoder (elementwise). XLA-exact rounding.
// ---------------------------------------------------------------------------
__global__ void spike_encode_kernel(const float* __restrict__ x,
                                    unsigned short* __restrict__ s1, int n)
{
    int i = blockIdx.x * blockDim.x + threadIdx.x;
    if (i >= n) return;
    float xv = x[i];
    float v = 0.0f;
#pragma unroll
    for (int t = 0; t < TSTEPS; ++t) {
        v = __fadd_rn(v, __fmul_rn(__fsub_rn(xv, v), 0.5f));
        bool sp = (v >= 1.0f);
        s1[(size_t)t * n + i] = sp ? 0x3F80 : 0;   // bf16 1.0 / 0.0
        v = sp ? 0.0f : v;
    }
}

// ---------------------------------------------------------------------------
// Weight prep, all 3 matrices in one launch.
// W [K][N] fp32 -> hiT, loT [N][K] bf16 (2-term split, transposed).
// ---------------------------------------------------------------------------
__global__ void split_transpose_all(const float* __restrict__ enc_W,
                                    const float* __restrict__ W_cells,
                                    bf16_t* __restrict__ W1h, bf16_t* __restrict__ W1l,
                                    bf16_t* __restrict__ W2h, bf16_t* __restrict__ W2l,
                                    bf16_t* __restrict__ W3h, bf16_t* __restrict__ W3l)
{
    const int N = 1024;
    const float* W;
    bf16_t *hi, *lo;
    int K;
    if (blockIdx.z == 0) {
        if (blockIdx.x >= 4) return;
        W = enc_W; hi = W1h; lo = W1l; K = 128;
    } else if (blockIdx.z == 1) {
        W = W_cells; hi = W2h; lo = W2l; K = 1024;
    } else {
        W = W_cells + (size_t)1024 * 1024; hi = W3h; lo = W3l; K = 1024;
    }
    __shared__ float tile[32][33];
    int k0 = blockIdx.x * 32, n0 = blockIdx.y * 32;
    int tx = threadIdx.x & 31, ty = threadIdx.x >> 5;
    for (int kk = ty; kk < 32; kk += 8)
        tile[kk][tx] = W[(size_t)(k0 + kk) * N + n0 + tx];
    __syncthreads();
    for (int nn = ty; nn < 32; nn += 8) {
        float w = tile[tx][nn];
        bf16_t h = (bf16_t)w;
        bf16_t l = (bf16_t)(w - (float)h);
        size_t o = (size_t)(n0 + nn) * K + (k0 + tx);
        hi[o] = h;
        lo[o] = l;
    }
}

// ---------------------------------------------------------------------------
// Fused MFMA GEMM + multistep LIF.  R8: t-folded K-loop (tau=4) at 2 w/SIMD.
// A: spikes [T][M][K] bf16 (0/1 exact). WhiT/WloT: [N][K] bf16 split weights.
// Block: 512 threads, 128x128 tile, 8 waves of 64x32 (2m x 4n),
// mfma_f32_32x32x16_bf16, acc[4t][2mt] (128 VGPR).
// Per k-iter: stage A for ALL 4 t (32KB) + B hi/lo ONCE (16KB) -> 32 MFMAs
// per wave (4x R7's arithmetic per staged B byte); 20 ds_read_b128/wave.
// Ring-2 LDS + vmcnt(6) + raw barriers (R7 sync, 64 barriers/gemm).
// Per-t k-summation tree identical to R4 (passed absmax 0.0).
//
// LDS swizzle (HW-verified R3): chunk i -> row r=i>>2, k-quad
// kq = ((i&3) - r - (r>>2)) & 3; frag read slot p = (s + row + (row>>2)) & 3.
// ---------------------------------------------------------------------------
template <int K, bool LAST>
__global__ __launch_bounds__(512, 2)
void gemm_lif_mfma(const unsigned short* __restrict__ A,
                   const bf16_t* __restrict__ WhiT,
                   const bf16_t* __restrict__ WloT,
                   const float* __restrict__ bias,
                   unsigned short* __restrict__ Sout,
                   float* __restrict__ Out,
                   int M, int N)
{
    constexpr int BK = 32;
    constexpr int NK = K / BK;
    __shared__ bf16_t As[2][4 * 4096];   // [buf][t*4096 + chunk*8] : 32 KB/buf
    __shared__ bf16_t Bb[2][2 * 4096];   // [buf][term*4096 + chunk*8] : 16 KB/buf

    const int tid = threadIdx.x;
    const int lane = tid & 63;
    const int wid = tid >> 6;            // 0..7
    const int l31 = lane & 31;
    const int half = lane >> 5;
    const int wave_m = (wid >> 2) * 64;  // 0 / 64
    const int wave_n = (wid & 3) * 32;   // 0,32,64,96
    const int m0 = blockIdx.x * 128;
    const int n0 = blockIdx.y * 128;

    // --- staging: thread tid owns chunk i=tid of each of the 6 slabs ---
    const int r = tid >> 2;                        // 0..127
    const int kq = ((tid & 3) - r - (r >> 2)) & 3;
    const int ldsW = wid * 512;                    // elems; wave-uniform

    const size_t tPlane = (size_t)M * K * 2;
    const char* Abase = (const char*)A + (size_t)(m0 + r) * K * 2 + kq * 16;
    const char* pBh = (const char*)WhiT + (size_t)(n0 + r) * K * 2 + kq * 16;
    const char* pBl = (const char*)WloT + (size_t)(n0 + r) * K * 2 + kq * 16;

    // --- fragment LDS byte offsets (within one buffer) ---
    int offA[2][2], offB[2];
#pragma unroll
    for (int mt = 0; mt < 2; ++mt)
#pragma unroll
        for (int ks = 0; ks < 2; ++ks) {
            int row = wave_m + mt * 32 + l31;
            int s = ks * 2 + half;
            offA[mt][ks] = row * 64 + (((s + row + (row >> 2)) & 3) << 4);
        }
    {
        int rowB = wave_n + l31;
#pragma unroll
        for (int ks = 0; ks < 2; ++ks) {
            int s = ks * 2 + half;
            offB[ks] = rowB * 64 + (((s + rowB + (rowB >> 2)) & 3) << 4);
        }
    }

    const float bv = bias[n0 + wave_n + l31];

    f32x16 acc[TSTEPS][2];
#pragma unroll
    for (int t = 0; t < TSTEPS; ++t)
#pragma unroll
        for (int mt = 0; mt < 2; ++mt)
            for (int rr = 0; rr < 16; ++rr) acc[t][mt][rr] = 0.0f;

    // prologue: chunk 0 -> buf 0 (6 DMA per thread)
#pragma unroll
    for (int t = 0; t < TSTEPS; ++t)
        glds16(Abase + t * tPlane, &As[0][t * 4096 + ldsW]);
    glds16(pBh, &Bb[0][0 + ldsW]);
    glds16(pBl, &Bb[0][4096 + ldsW]);

    for (int kk = 0; kk < NK; ++kk) {
        const int cur = kk & 1;

        if (kk + 1 < NK) {
            const int nxt = cur ^ 1;
            const size_t kb = (size_t)(kk + 1) * 64;   // BK*2 bytes
#pragma unroll
            for (int t = 0; t < TSTEPS; ++t)
                glds16(Abase + t * tPlane + kb, &As[nxt][t * 4096 + ldsW]);
            glds16(pBh + kb, &Bb[nxt][0 + ldsW]);
            glds16(pBl + kb, &Bb[nxt][4096 + ldsW]);
            __builtin_amdgcn_s_waitcnt(WAITCNT_VM6);   // k's 6 loads landed
        } else {
            __builtin_amdgcn_s_waitcnt(WAITCNT_VM0);
        }
        asm volatile("" ::: "memory");
        __builtin_amdgcn_s_barrier();   // raw: no vmcnt(0) drain
        asm volatile("" ::: "memory");

#pragma unroll
        for (int ks = 0; ks < 2; ++ks) {
            bf16x8 fbh = *(const bf16x8*)((const char*)&Bb[cur][0] + offB[ks]);
            bf16x8 fbl = *(const bf16x8*)((const char*)&Bb[cur][4096] + offB[ks]);
#pragma unroll
            for (int t = 0; t < TSTEPS; ++t)
#pragma unroll
                for (int mt = 0; mt < 2; ++mt) {
                    bf16x8 a = *(const bf16x8*)(
                        (const char*)&As[cur][t * 4096] + offA[mt][ks]);
                    acc[t][mt] = __builtin_amdgcn_mfma_f32_32x32x16_bf16(
                        a, fbh, acc[t][mt], 0, 0, 0);
                    acc[t][mt] = __builtin_amdgcn_mfma_f32_32x32x16_bf16(
                        a, fbl, acc[t][mt], 0, 0, 0);
                }
        }
        asm volatile("" ::: "memory");
        __builtin_amdgcn_s_barrier();   // WAR sync before buf reuse
        asm volatile("" ::: "memory");
    }

    // --- LIF epilogue: t-scan in registers (XLA-exact arithmetic) ---
    f32x16 v[2];
    uint64_t bits[2] = {0ull, 0ull};
#pragma unroll
    for (int mt = 0; mt < 2; ++mt)
        for (int rr = 0; rr < 16; ++rr) v[mt][rr] = 0.0f;

#pragma unroll
    for (int t = 0; t < TSTEPS; ++t)
#pragma unroll
        for (int mt = 0; mt < 2; ++mt)
#pragma unroll
            for (int rr = 0; rr < 16; ++rr) {
                float y = __fadd_rn(acc[t][mt][rr], bv);
                float vv = v[mt][rr];
                vv = __fadd_rn(vv, __fmul_rn(__fsub_rn(y, vv), 0.5f));
                bool sp = (vv >= 1.0f);
                v[mt][rr] = sp ? 0.0f : vv;
                if (LAST) {
                    bits[mt] |= sp ? (1ull << (rr * 4 + t)) : 0ull;
                } else {
                    int row = (rr & 3) + 8 * (rr >> 2) + 4 * half;
                    int m = m0 + wave_m + mt * 32 + row;
                    int n = n0 + wave_n + l31;
                    Sout[(size_t)t * M * N + (size_t)m * N + n] = sp ? 0x3F80 : 0;
                }
            }

    if (LAST) {
#pragma unroll
        for (int mt = 0; mt < 2; ++mt)
#pragma unroll
            for (int rr = 0; rr < 16; ++rr) {
                int row = (rr & 3) + 8 * (rr >> 2) + 4 * half;
                int m = m0 + wave_m + mt * 32 + row;
                int n = n0 + wave_n + l31;
                int cnt = __popc((unsigned)((bits[mt] >> (rr * 4)) & 0xFull));
                Out[(size_t)m * N + n] = 0.25f * (float)cnt;
            }
    }
}

// ---------------------------------------------------------------------------
// out2[b][d] = mean over L of out[b][l][d]. Exact in fp32 (quarter-integers).
// ---------------------------------------------------------------------------
__global__ void mean_over_L_kernel(const float* __restrict__ out,
                                   float* __restrict__ out2,
                                   int B, int L, int D)
{
    int id = blockIdx.x * blockDim.x + threadIdx.x;
    if (id >= B * D) return;
    int b = id / D, d = id - b * D;
    const float* p = out + (size_t)b * L * D + d;
    float s = 0.0f;
    for (int l = 0; l < L; ++l) s += p[(size_t)l * D];
    out2[id] = s * (1.0f / (float)L);
}

// ---------------------------------------------------------------------------
extern "C" void kernel_launch(void* const* d_in, const int* in_sizes, int n_in,
                              void* d_out, int out_size, void* d_ws, size_t ws_size,
                              hipStream_t stream)
{
    const float* inputs  = (const float*)d_in[0];  // [16,512,128]
    const float* enc_W   = (const float*)d_in[1];  // [128,1024]
    const float* enc_b   = (const float*)d_in[2];  // [1024]
    const float* W_cells = (const float*)d_in[3];  // [2,1024,1024]
    const float* b_cells = (const float*)d_in[4];  // [2,1024]

    const int B = 16, L = 512, C = 128, D = 1024;
    const int M = B * L;  // 8192

    // ws layout: s1 8MB | W1h/l 0.5MB | W2h/l 4MB | W3h/l 4MB | h0 64MB | h1 64MB
    char* ws = (char*)d_ws;
    size_t off = 0;
    unsigned short* s1 = (unsigned short*)(ws + off); off += (size_t)TSTEPS * M * C * 2;
    bf16_t* W1h = (bf16_t*)(ws + off); off += (size_t)C * D * 2;
    bf16_t* W1l = (bf16_t*)(ws + off); off += (size_t)C * D * 2;
    bf16_t* W2h = (bf16_t*)(ws + off); off += (size_t)D * D * 2;
    bf16_t* W2l = (bf16_t*)(ws + off); off += (size_t)D * D * 2;
    bf16_t* W3h = (bf16_t*)(ws + off); off += (size_t)D * D * 2;
    bf16_t* W3l = (bf16_t*)(ws + off); off += (size_t)D * D * 2;
    unsigned short* h0 = (unsigned short*)(ws + off); off += (size_t)TSTEPS * M * D * 2;
    unsigned short* h1 = (unsigned short*)(ws + off);

    float* out  = (float*)d_out;          // [M, D]
    float* out2 = out + (size_t)M * D;    // [B, D]

    split_transpose_all<<<dim3(32, 32, 3), 256, 0, stream>>>(
        enc_W, W_cells, W1h, W1l, W2h, W2l, W3h, W3l);

    const int n1 = M * C;
    spike_encode_kernel<<<(n1 + 255) / 256, 256, 0, stream>>>(inputs, s1, n1);

    dim3 grid(M / 128, D / 128);
    gemm_lif_mfma<128, false><<<grid, 512, 0, stream>>>(
        s1, W1h, W1l, enc_b, h0, nullptr, M, D);
    gemm_lif_mfma<1024, false><<<grid, 512, 0, stream>>>(
        h0, W2h, W2l, b_cells, h1, nullptr, M, D);
    gemm_lif_mfma<1024, true><<<grid, 512, 0, stream>>>(
        h1, W3h, W3l, b_cells + D, nullptr, out, M, D);

    mean_over_L_kernel<<<(B * D + 255) / 256, 256, 0, stream>>>(
        out, out2, B, L, D);
}